// Round 2
// baseline (1019.974 us; speedup 1.0000x reference)
//
#include <hip/hip_runtime.h>
#include <math.h>

// B=8, G=2048, K=32, N=64.
// Algebraic simplification (verified): e_x is constant along the K axis that
// up/down average over => k_anp_x = mean(ff,K) exactly; std_dev/p/nrm/lc/e_x
// branch is dead code. kl = 2*mean(ff,K); the norm over G cancels the 2.
//
//  k1/k1f : global std(diff, ddof=1) (two-stage double reduce)
//  k2     : per (b,g,k) row: knn_line(68) @ fourier_B(68x32), sin/cos via
//           exact revolution reduction + v_sin/v_cos, mean over K -> M[b,g,c]
//  k3p/k3r: inv_r[b,c] = 1/||M[b,:,c]||_G  (coalesced 2-stage)
//  k3b    : out[b,c,g] = gelu(M*inv_r) - lc_line ; out[b,64+c,g] = lc_line

constexpr int Gg = 2048;

// ws layout (bytes); PART region is reused by k3_part (both 32768 B).
constexpr size_t PART_OFF = 0;       // k1: 2048*2 doubles; k3p: 128*64 f32
constexpr size_t STD_OFF  = 32768;   // 1 float
constexpr size_t INVR_OFF = 33024;   // 512 floats
constexpr size_t M_OFF    = 65536;   // 8*2048*64 floats = 4 MiB

// ---------------- K1: partial sums for global std ----------------
__global__ __launch_bounds__(256) void k1_partial(const float4* __restrict__ knn4,
                                                  const float4* __restrict__ lc4,
                                                  double* __restrict__ part)
{
    int tid  = threadIdx.x;
    int base = blockIdx.x * 256 + tid;
    float4 q[16];
    #pragma unroll
    for (int i = 0; i < 16; ++i) q[i] = knn4[base + i * 524288];  // all loads in flight
    double s = 0.0, s2 = 0.0;
    #pragma unroll
    for (int i = 0; i < 16; ++i) {
        int idx = base + i * 524288;
        float4 l = lc4[(idx >> 9) * 16 + (idx & 15)];
        float d0 = q[i].x - l.x, d1 = q[i].y - l.y, d2 = q[i].z - l.z, d3 = q[i].w - l.w;
        s += (double)d0; s += (double)d1; s += (double)d2; s += (double)d3;
        s2 = fma((double)d0, (double)d0, s2);
        s2 = fma((double)d1, (double)d1, s2);
        s2 = fma((double)d2, (double)d2, s2);
        s2 = fma((double)d3, (double)d3, s2);
    }
    __shared__ double sh[512];
    sh[tid] = s; sh[256 + tid] = s2;
    __syncthreads();
    for (int off = 128; off > 0; off >>= 1) {
        if (tid < off) { sh[tid] += sh[tid + off]; sh[256 + tid] += sh[256 + tid + off]; }
        __syncthreads();
    }
    if (tid == 0) { part[blockIdx.x * 2] = sh[0]; part[blockIdx.x * 2 + 1] = sh[256]; }
}

__global__ __launch_bounds__(256) void k1_final(const double* __restrict__ part,
                                                float* __restrict__ stdp)
{
    int tid = threadIdx.x;
    double s = 0.0, s2 = 0.0;
    for (int i = tid; i < 2048; i += 256) { s += part[2*i]; s2 += part[2*i+1]; }
    __shared__ double sh[512];
    sh[tid] = s; sh[256 + tid] = s2;
    __syncthreads();
    for (int off = 128; off > 0; off >>= 1) {
        if (tid < off) { sh[tid] += sh[tid + off]; sh[256 + tid] += sh[256 + tid + off]; }
        __syncthreads();
    }
    if (tid == 0) {
        double S = sh[0], S2 = sh[256];
        double Mn = 33554432.0;
        double var = (S2 - S * S / Mn) / (Mn - 1.0);
        stdp[0] = (float)sqrt(var);
    }
}

// ---------------- K2: main fused kernel ----------------
__global__ __launch_bounds__(256, 3) void k2_main(const float* __restrict__ knn,
                                                  const float* __restrict__ lc,
                                                  const float* __restrict__ fB,
                                                  const float* __restrict__ stdp,
                                                  float* __restrict__ M)
{
    const int tid = threadIdx.x;
    const int row = blockIdx.x * 256 + tid;   // (b*G+g)*K + k
    const int grp = tid >> 5;                 // 0..7 : which (b,g) in block

    __shared__ float4 lcs[8][16];
    __shared__ float  red[8][64];

    if (tid < 128)
        lcs[tid >> 4][tid & 15] =
            ((const float4*)lc)[(size_t)(blockIdx.x * 8 + (tid >> 4)) * 16 + (tid & 15)];

    // whole row into registers: 16 dwordx4 in flight before any compute
    const float4* kq = (const float4*)knn + (size_t)row * 16;
    float4 q[16];
    #pragma unroll
    for (int i = 0; i < 16; ++i) q[i] = kq[i];

    __syncthreads();
    const float inv = 1.0f / (stdp[0] + 1e-5f);

    float acc[32];
    #pragma unroll
    for (int c = 0; c < 32; ++c) acc[c] = 0.0f;
    float dot = 0.0f;
    float kn0 = 0, kn1 = 0, kn2 = 0, ln0 = 0, ln1 = 0, ln2 = 0;

    #pragma unroll
    for (int j4 = 0; j4 < 16; ++j4) {
        float4 l = lcs[grp][j4];
        float e0 = (q[j4].x - l.x) * inv;
        float e1 = (q[j4].y - l.y) * inv;
        float e2 = (q[j4].z - l.z) * inv;
        float e3 = (q[j4].w - l.w) * inv;
        if (j4 == 0) { kn0 = e0; kn1 = e1; kn2 = e2; ln0 = l.x; ln1 = l.y; ln2 = l.z; }
        dot = fmaf(e0, l.x, dot);
        dot = fmaf(e1, l.y, dot);
        dot = fmaf(e2, l.z, dot);
        dot = fmaf(e3, l.w, dot);
        const float* fr = fB + j4 * 128;   // uniform address -> s_load
        #pragma unroll
        for (int c = 0; c < 32; ++c) acc[c] = fmaf(e0, fr[c],      acc[c]);
        #pragma unroll
        for (int c = 0; c < 32; ++c) acc[c] = fmaf(e1, fr[32 + c], acc[c]);
        #pragma unroll
        for (int c = 0; c < 32; ++c) acc[c] = fmaf(e2, fr[64 + c], acc[c]);
        #pragma unroll
        for (int c = 0; c < 32; ++c) acc[c] = fmaf(e3, fr[96 + c], acc[c]);
    }

    // descending sort3 of normalized knn[0:3] and raw lc[0:3]
    float a0 = kn0, a1 = kn1, a2 = kn2;
    float b0 = ln0, b1 = ln1, b2 = ln2;
    float t;
    if (a0 < a1) { t = a0; a0 = a1; a1 = t; }
    if (a1 < a2) { t = a1; a1 = a2; a2 = t; }
    if (a0 < a1) { t = a0; a0 = a1; a1 = t; }
    if (b0 < b1) { t = b0; b0 = b1; b1 = t; }
    if (b1 < b2) { t = b1; b1 = b2; b2 = t; }
    if (b0 < b1) { t = b0; b0 = b1; b1 = t; }

    float cr0 = a1 * b2 - a2 * b1;
    float cr1 = a2 * b0 - a0 * b2;
    float cr2 = a0 * b1 - a1 * b0;
    {
        const float* fr = fB + 64 * 32;
        #pragma unroll
        for (int c = 0; c < 32; ++c) acc[c] = fmaf(cr0, fr[c],      acc[c]);
        #pragma unroll
        for (int c = 0; c < 32; ++c) acc[c] = fmaf(cr1, fr[32 + c], acc[c]);
        #pragma unroll
        for (int c = 0; c < 32; ++c) acc[c] = fmaf(cr2, fr[64 + c], acc[c]);
        #pragma unroll
        for (int c = 0; c < 32; ++c) acc[c] = fmaf(dot, fr[96 + c], acc[c]);
    }

    // sin(2*pi*acc), cos(2*pi*acc): exact revolution reduction + hw sin/cos.
    // r = acc - rintf(acc) is exact (Sterbenz); v_sin/v_cos take revolutions.
    #pragma unroll
    for (int c = 0; c < 32; ++c) {
        float a = acc[c];
        float r = a - rintf(a);
        float sv = __builtin_amdgcn_sinf(r);
        float cv = __builtin_amdgcn_cosf(r);
        #pragma unroll
        for (int m = 1; m <= 16; m <<= 1) {
            sv += __shfl_xor(sv, m);
            cv += __shfl_xor(cv, m);
        }
        if ((tid & 31) == 0) {
            red[grp][c]      = sv * (1.0f / 32.0f);
            red[grp][32 + c] = cv * (1.0f / 32.0f);
        }
    }
    __syncthreads();
    const int c2   = (tid & 31) * 2;
    const int mrow = blockIdx.x * 8 + grp;      // = b*G+g
    float2 v = make_float2(red[grp][c2], red[grp][c2 + 1]);
    *(float2*)(M + (size_t)mrow * 64 + c2) = v;
}

// ---------------- K3p: per-(b,gb) partial ssq over 128 g, coalesced ----------------
__global__ __launch_bounds__(256) void k3_part(const float* __restrict__ M,
                                               float* __restrict__ part2)
{
    int blk = blockIdx.x;                 // b*16 + gb
    int b = blk >> 4, gb = blk & 15;
    int t = threadIdx.x;
    int c = t & 63, gs = t >> 6;          // 0..3
    const float* base = M + ((size_t)(b * Gg + gb * 128 + gs)) * 64 + c;
    float ss = 0.0f;
    #pragma unroll
    for (int i = 0; i < 32; ++i) {        // g = gb*128 + gs + 4*i
        float v = base[(size_t)i * 256];
        ss = fmaf(v, v, ss);
    }
    __shared__ float sh[256];
    sh[t] = ss;
    __syncthreads();
    if (t < 64) part2[blk * 64 + t] = sh[t] + sh[t + 64] + sh[t + 128] + sh[t + 192];
}

__global__ __launch_bounds__(64) void k3_rfin(const float* __restrict__ part2,
                                              float* __restrict__ invr)
{
    int b = blockIdx.x, c = threadIdx.x;
    float s = 0.0f;
    #pragma unroll
    for (int gb = 0; gb < 16; ++gb) s += part2[(b * 16 + gb) * 64 + c];
    invr[b * 64 + c] = 1.0f / sqrtf(s);
}

// ---------------- K3b: finalize ----------------
__global__ __launch_bounds__(256) void k3_final(const float* __restrict__ M,
                                                const float* __restrict__ lc,
                                                const float* __restrict__ invr,
                                                float* __restrict__ out)
{
    __shared__ float mt[64][65];
    __shared__ float lt[64][65];
    __shared__ float ir[64];
    __shared__ float iln[64];
    int tid = threadIdx.x;
    int b  = blockIdx.x >> 5;
    int g0 = (blockIdx.x & 31) * 64;
    if (tid < 64) ir[tid] = invr[b * 64 + tid];
    const float* Mb = M  + ((size_t)(b * Gg + g0)) * 64;
    const float* Lb = lc + ((size_t)(b * Gg + g0)) * 64;
    #pragma unroll
    for (int i = 0; i < 4; ++i) {
        int f = i * 1024 + tid * 4;
        int r = f >> 6, col = f & 63;
        float4 mv = *(const float4*)(Mb + f);
        float4 lv = *(const float4*)(Lb + f);
        mt[r][col] = mv.x; mt[r][col+1] = mv.y; mt[r][col+2] = mv.z; mt[r][col+3] = mv.w;
        lt[r][col] = lv.x; lt[r][col+1] = lv.y; lt[r][col+2] = lv.z; lt[r][col+3] = lv.w;
    }
    __syncthreads();
    if (tid < 64) {
        float ss = 0.0f;
        #pragma unroll
        for (int c = 0; c < 64; ++c) { float v = lt[tid][c]; ss = fmaf(v, v, ss); }
        iln[tid] = 1.0f / sqrtf(ss);
    }
    __syncthreads();
    int gl = tid & 63;
    int c0 = tid >> 6;                    // 0..3, wave-uniform
    float il = iln[gl];
    int obase = (b * 128) * Gg + g0 + gl;
    #pragma unroll
    for (int i = 0; i < 16; ++i) {
        int c = c0 + i * 4;
        float lcl = lt[gl][c] * il;
        float x = mt[gl][c] * ir[c];
        float kl = 0.5f * x * (1.0f + erff(x * 0.70710678118654752f));
        out[obase + c * Gg]        = kl - lcl;   // line_element
        out[obase + (c + 64) * Gg] = lcl;        // lc_line
    }
}

extern "C" void kernel_launch(void* const* d_in, const int* in_sizes, int n_in,
                              void* d_out, int out_size, void* d_ws, size_t ws_size,
                              hipStream_t stream)
{
    (void)in_sizes; (void)n_in; (void)out_size; (void)ws_size;
    const float* lc  = (const float*)d_in[0];   // (8,2048,64)
    const float* knn = (const float*)d_in[1];   // (8,2048,32,64)
    const float* fB  = (const float*)d_in[2];   // (68,32)
    float* out = (float*)d_out;                 // (8,128,2048) f32
    char* ws = (char*)d_ws;
    double* part  = (double*)(ws + PART_OFF);
    float*  part2 = (float*)(ws + PART_OFF);    // reused after k1_final consumed it
    float*  stdp  = (float*)(ws + STD_OFF);
    float*  invr  = (float*)(ws + INVR_OFF);
    float*  M     = (float*)(ws + M_OFF);

    hipLaunchKernelGGL(k1_partial, dim3(2048), dim3(256), 0, stream,
                       (const float4*)knn, (const float4*)lc, part);
    hipLaunchKernelGGL(k1_final, dim3(1), dim3(256), 0, stream, part, stdp);
    hipLaunchKernelGGL(k2_main, dim3(2048), dim3(256), 0, stream,
                       knn, lc, fB, stdp, M);
    hipLaunchKernelGGL(k3_part, dim3(128), dim3(256), 0, stream, M, part2);
    hipLaunchKernelGGL(k3_rfin, dim3(8), dim3(64), 0, stream, part2, invr);
    hipLaunchKernelGGL(k3_final, dim3(256), dim3(256), 0, stream, M, lc, invr, out);
}

// Round 3
// 117.179 us; speedup vs baseline: 8.7044x; 8.7044x over previous
//
#include <hip/hip_runtime.h>
#include <math.h>

// B=8, G=2048, K=32, N=64.
// Algebraic simplification (verified): e_x is constant along the K axis that
// up/down average over => k_anp_x = mean(ff,K) exactly; std_dev/p/nrm/lc/e_x
// branch is dead code. kl = 2*mean(ff,K); the norm over G cancels the 2.
//
//  k1/k1f : global std(diff, ddof=1) (two-stage double reduce)
//  k2     : stage 64KB knn tile to LDS via global_load_lds (rotation swizzle
//           pre-applied on the global src addr), per-row 68 @ fB(68x32),
//           deferred 1/std scale, exact revolution reduction + v_sin/v_cos,
//           mean over K -> M[b,g,c]
//  k3p/k3r: inv_r[b,c] = 1/||M[b,:,c]||_G  (coalesced 2-stage)
//  k3b    : out[b,c,g] = gelu(M*inv_r) - lc_line ; out[b,64+c,g] = lc_line

constexpr int Gg = 2048;

constexpr size_t PART_OFF = 0;       // k1: 2048*2 doubles; k3p: 128*64 f32
constexpr size_t STD_OFF  = 32768;   // 1 float
constexpr size_t INVR_OFF = 33024;   // 512 floats
constexpr size_t M_OFF    = 65536;   // 8*2048*64 floats = 4 MiB

// ---------------- K1: partial sums for global std ----------------
__global__ __launch_bounds__(256) void k1_partial(const float4* __restrict__ knn4,
                                                  const float4* __restrict__ lc4,
                                                  double* __restrict__ part)
{
    int tid  = threadIdx.x;
    int base = blockIdx.x * 256 + tid;
    float4 q[16];
    #pragma unroll
    for (int i = 0; i < 16; ++i) q[i] = knn4[base + i * 524288];
    double s = 0.0, s2 = 0.0;
    #pragma unroll
    for (int i = 0; i < 16; ++i) {
        int idx = base + i * 524288;
        float4 l = lc4[(idx >> 9) * 16 + (idx & 15)];
        float d0 = q[i].x - l.x, d1 = q[i].y - l.y, d2 = q[i].z - l.z, d3 = q[i].w - l.w;
        s += (double)d0; s += (double)d1; s += (double)d2; s += (double)d3;
        s2 = fma((double)d0, (double)d0, s2);
        s2 = fma((double)d1, (double)d1, s2);
        s2 = fma((double)d2, (double)d2, s2);
        s2 = fma((double)d3, (double)d3, s2);
    }
    __shared__ double sh[512];
    sh[tid] = s; sh[256 + tid] = s2;
    __syncthreads();
    for (int off = 128; off > 0; off >>= 1) {
        if (tid < off) { sh[tid] += sh[tid + off]; sh[256 + tid] += sh[256 + tid + off]; }
        __syncthreads();
    }
    if (tid == 0) { part[blockIdx.x * 2] = sh[0]; part[blockIdx.x * 2 + 1] = sh[256]; }
}

__global__ __launch_bounds__(256) void k1_final(const double* __restrict__ part,
                                                float* __restrict__ stdp)
{
    int tid = threadIdx.x;
    double s = 0.0, s2 = 0.0;
    for (int i = tid; i < 2048; i += 256) { s += part[2*i]; s2 += part[2*i+1]; }
    __shared__ double sh[512];
    sh[tid] = s; sh[256 + tid] = s2;
    __syncthreads();
    for (int off = 128; off > 0; off >>= 1) {
        if (tid < off) { sh[tid] += sh[tid + off]; sh[256 + tid] += sh[256 + tid + off]; }
        __syncthreads();
    }
    if (tid == 0) {
        double S = sh[0], S2 = sh[256];
        double Mn = 33554432.0;
        double var = (S2 - S * S / Mn) / (Mn - 1.0);
        stdp[0] = (float)sqrt(var);
    }
}

// ---------------- K2: main fused kernel ----------------
// LDS tile layout: row r (0..255) x slot s (0..15); slot s holds global
// chunk j=(s-r)&15 of the row. global_load_lds writes linearly (base+lane*16)
// so the rotation is applied on the per-lane global SOURCE address; the
// per-row ds_read_b128 at slot (j+r)&15 is then bank-conflict-free.
__global__ __launch_bounds__(256) void k2_main(const float* __restrict__ knn,
                                               const float* __restrict__ lc,
                                               const float* __restrict__ fB,
                                               const float* __restrict__ stdp,
                                               float* __restrict__ M)
{
    __shared__ float4 tile[4096];      // 64 KB
    __shared__ float4 lcs[8][17];      // padded: two wave-halves hit diff banks
    __shared__ float  red[8][64];

    const int tid  = threadIdx.x;
    const int wave = tid >> 6;
    const int lane = tid & 63;

    const char* gbase = (const char*)knn + (size_t)blockIdx.x * 65536;
    #pragma unroll
    for (int i = 0; i < 16; ++i) {
        int rr = wave * 64 + i * 4 + (lane >> 4);          // row in tile
        int j  = ((lane & 15) - rr) & 15;                  // source chunk
        const void* src = gbase + (size_t)rr * 256 + (size_t)j * 16;
        void* dst = (char*)tile + wave * 16384 + i * 1024; // wave-uniform
        __builtin_amdgcn_global_load_lds(src, dst, 16, 0, 0);
    }
    if (tid < 128)
        lcs[tid >> 4][tid & 15] =
            ((const float4*)lc)[(size_t)(blockIdx.x * 8 + (tid >> 4)) * 16 + (tid & 15)];
    __syncthreads();

    const float inv = 1.0f / (stdp[0] + 1e-5f);
    const int grp = tid >> 5;
    const float4* myrow = tile + tid * 16;

    float acc[32];
    #pragma unroll
    for (int c = 0; c < 32; ++c) acc[c] = 0.0f;

    // j = 0 peeled (slot tid&15): capture raw d[0:3] and lc[0:3]
    float4 q0 = myrow[tid & 15];
    float4 l0 = lcs[grp][0];
    float d0 = q0.x - l0.x, d1 = q0.y - l0.y, d2 = q0.z - l0.z, d3 = q0.w - l0.w;
    float dot = d0 * l0.x;
    dot = fmaf(d1, l0.y, dot);
    dot = fmaf(d2, l0.z, dot);
    dot = fmaf(d3, l0.w, dot);
    float kn0 = d0, kn1 = d1, kn2 = d2;
    float ln0 = l0.x, ln1 = l0.y, ln2 = l0.z;
    {
        const float* fr = fB;
        #pragma unroll
        for (int c = 0; c < 32; ++c) acc[c] = fmaf(d0, fr[c],      acc[c]);
        #pragma unroll
        for (int c = 0; c < 32; ++c) acc[c] = fmaf(d1, fr[32 + c], acc[c]);
        #pragma unroll
        for (int c = 0; c < 32; ++c) acc[c] = fmaf(d2, fr[64 + c], acc[c]);
        #pragma unroll
        for (int c = 0; c < 32; ++c) acc[c] = fmaf(d3, fr[96 + c], acc[c]);
    }
    for (int j = 1; j < 16; ++j) {
        float4 q = myrow[(j + tid) & 15];
        float4 l = lcs[grp][j];
        float e0 = q.x - l.x;
        float e1 = q.y - l.y;
        float e2 = q.z - l.z;
        float e3 = q.w - l.w;
        dot = fmaf(e0, l.x, dot);
        dot = fmaf(e1, l.y, dot);
        dot = fmaf(e2, l.z, dot);
        dot = fmaf(e3, l.w, dot);
        const float* fr = fB + j * 128;
        #pragma unroll
        for (int c = 0; c < 32; ++c) acc[c] = fmaf(e0, fr[c],      acc[c]);
        #pragma unroll
        for (int c = 0; c < 32; ++c) acc[c] = fmaf(e1, fr[32 + c], acc[c]);
        #pragma unroll
        for (int c = 0; c < 32; ++c) acc[c] = fmaf(e2, fr[64 + c], acc[c]);
        #pragma unroll
        for (int c = 0; c < 32; ++c) acc[c] = fmaf(e3, fr[96 + c], acc[c]);
    }

    // descending sort3 of raw d[0:3] (same order as normalized) and lc[0:3]
    float a0 = kn0, a1 = kn1, a2 = kn2;
    float b0 = ln0, b1 = ln1, b2 = ln2;
    float t;
    if (a0 < a1) { t = a0; a0 = a1; a1 = t; }
    if (a1 < a2) { t = a1; a1 = a2; a2 = t; }
    if (a0 < a1) { t = a0; a0 = a1; a1 = t; }
    if (b0 < b1) { t = b0; b0 = b1; b1 = t; }
    if (b1 < b2) { t = b1; b1 = b2; b2 = t; }
    if (b0 < b1) { t = b0; b0 = b1; b1 = t; }

    float cr0 = a1 * b2 - a2 * b1;     // raw cross; inv scales through
    float cr1 = a2 * b0 - a0 * b2;
    float cr2 = a0 * b1 - a1 * b0;
    {
        const float* fr = fB + 64 * 32;
        #pragma unroll
        for (int c = 0; c < 32; ++c) acc[c] = fmaf(cr0, fr[c],      acc[c]);
        #pragma unroll
        for (int c = 0; c < 32; ++c) acc[c] = fmaf(cr1, fr[32 + c], acc[c]);
        #pragma unroll
        for (int c = 0; c < 32; ++c) acc[c] = fmaf(cr2, fr[64 + c], acc[c]);
        #pragma unroll
        for (int c = 0; c < 32; ++c) acc[c] = fmaf(dot, fr[96 + c], acc[c]);
    }

    // phase = inv*acc revolutions; exact reduction r = a - rint(a); hw sin/cos
    #pragma unroll
    for (int c = 0; c < 32; ++c) {
        float a = acc[c] * inv;
        float r = a - rintf(a);
        float sv = __builtin_amdgcn_sinf(r);
        float cv = __builtin_amdgcn_cosf(r);
        #pragma unroll
        for (int m = 1; m <= 16; m <<= 1) {
            sv += __shfl_xor(sv, m);
            cv += __shfl_xor(cv, m);
        }
        if ((tid & 31) == 0) {
            red[grp][c]      = sv * (1.0f / 32.0f);
            red[grp][32 + c] = cv * (1.0f / 32.0f);
        }
    }
    __syncthreads();
    const int c2   = (tid & 31) * 2;
    const int mrow = blockIdx.x * 8 + grp;      // = b*G+g
    float2 v = make_float2(red[grp][c2], red[grp][c2 + 1]);
    *(float2*)(M + (size_t)mrow * 64 + c2) = v;
}

// ---------------- K3p: per-(b,gb) partial ssq over 128 g, coalesced ----------------
__global__ __launch_bounds__(256) void k3_part(const float* __restrict__ M,
                                               float* __restrict__ part2)
{
    int blk = blockIdx.x;                 // b*16 + gb
    int b = blk >> 4, gb = blk & 15;
    int t = threadIdx.x;
    int c = t & 63, gs = t >> 6;          // 0..3
    const float* base = M + ((size_t)(b * Gg + gb * 128 + gs)) * 64 + c;
    float ss = 0.0f;
    #pragma unroll
    for (int i = 0; i < 32; ++i) {        // g = gb*128 + gs + 4*i
        float v = base[(size_t)i * 256];
        ss = fmaf(v, v, ss);
    }
    __shared__ float sh[256];
    sh[t] = ss;
    __syncthreads();
    if (t < 64) part2[blk * 64 + t] = sh[t] + sh[t + 64] + sh[t + 128] + sh[t + 192];
}

__global__ __launch_bounds__(64) void k3_rfin(const float* __restrict__ part2,
                                              float* __restrict__ invr)
{
    int b = blockIdx.x, c = threadIdx.x;
    float s = 0.0f;
    #pragma unroll
    for (int gb = 0; gb < 16; ++gb) s += part2[(b * 16 + gb) * 64 + c];
    invr[b * 64 + c] = 1.0f / sqrtf(s);
}

// ---------------- K3b: finalize ----------------
__global__ __launch_bounds__(256) void k3_final(const float* __restrict__ M,
                                                const float* __restrict__ lc,
                                                const float* __restrict__ invr,
                                                float* __restrict__ out)
{
    __shared__ float mt[64][65];
    __shared__ float lt[64][65];
    __shared__ float ir[64];
    __shared__ float iln[64];
    int tid = threadIdx.x;
    int b  = blockIdx.x >> 5;
    int g0 = (blockIdx.x & 31) * 64;
    if (tid < 64) ir[tid] = invr[b * 64 + tid];
    const float* Mb = M  + ((size_t)(b * Gg + g0)) * 64;
    const float* Lb = lc + ((size_t)(b * Gg + g0)) * 64;
    #pragma unroll
    for (int i = 0; i < 4; ++i) {
        int f = i * 1024 + tid * 4;
        int r = f >> 6, col = f & 63;
        float4 mv = *(const float4*)(Mb + f);
        float4 lv = *(const float4*)(Lb + f);
        mt[r][col] = mv.x; mt[r][col+1] = mv.y; mt[r][col+2] = mv.z; mt[r][col+3] = mv.w;
        lt[r][col] = lv.x; lt[r][col+1] = lv.y; lt[r][col+2] = lv.z; lt[r][col+3] = lv.w;
    }
    __syncthreads();
    if (tid < 64) {
        float ss = 0.0f;
        #pragma unroll
        for (int c = 0; c < 64; ++c) { float v = lt[tid][c]; ss = fmaf(v, v, ss); }
        iln[tid] = 1.0f / sqrtf(ss);
    }
    __syncthreads();
    int gl = tid & 63;
    int c0 = tid >> 6;                    // 0..3, wave-uniform
    float il = iln[gl];
    int obase = (b * 128) * Gg + g0 + gl;
    #pragma unroll
    for (int i = 0; i < 16; ++i) {
        int c = c0 + i * 4;
        float lcl = lt[gl][c] * il;
        float x = mt[gl][c] * ir[c];
        float kl = 0.5f * x * (1.0f + erff(x * 0.70710678118654752f));
        out[obase + c * Gg]        = kl - lcl;   // line_element
        out[obase + (c + 64) * Gg] = lcl;        // lc_line
    }
}

extern "C" void kernel_launch(void* const* d_in, const int* in_sizes, int n_in,
                              void* d_out, int out_size, void* d_ws, size_t ws_size,
                              hipStream_t stream)
{
    (void)in_sizes; (void)n_in; (void)out_size; (void)ws_size;
    const float* lc  = (const float*)d_in[0];   // (8,2048,64)
    const float* knn = (const float*)d_in[1];   // (8,2048,32,64)
    const float* fB  = (const float*)d_in[2];   // (68,32)
    float* out = (float*)d_out;                 // (8,128,2048) f32
    char* ws = (char*)d_ws;
    double* part  = (double*)(ws + PART_OFF);
    float*  part2 = (float*)(ws + PART_OFF);
    float*  stdp  = (float*)(ws + STD_OFF);
    float*  invr  = (float*)(ws + INVR_OFF);
    float*  M     = (float*)(ws + M_OFF);

    hipLaunchKernelGGL(k1_partial, dim3(2048), dim3(256), 0, stream,
                       (const float4*)knn, (const float4*)lc, part);
    hipLaunchKernelGGL(k1_final, dim3(1), dim3(256), 0, stream, part, stdp);
    hipLaunchKernelGGL(k2_main, dim3(2048), dim3(256), 0, stream,
                       knn, lc, fB, stdp, M);
    hipLaunchKernelGGL(k3_part, dim3(128), dim3(256), 0, stream, M, part2);
    hipLaunchKernelGGL(k3_rfin, dim3(8), dim3(64), 0, stream, part2, invr);
    hipLaunchKernelGGL(k3_final, dim3(256), dim3(256), 0, stream, M, lc, invr, out);
}